// Round 9
// baseline (1211.283 us; speedup 1.0000x reference)
//
#include <hip/hip_runtime.h>
#include <hip/hip_fp16.h>

// Problem constants
#define RF    1024
#define USZ   200
#define NWIN  1600          // N = 8 * 200
#define SCALEF 0.70710678118f
#define L2E2  2.885390082f  // 2*log2(e)
#define L2E   1.442695041f  // log2(e)
#define TPB   512
#define CSTR  72            // act channel stride in halfs (144 B rows, conflict-free)

typedef _Float16 f16x8 __attribute__((ext_vector_type(8)));
typedef float    f32x4 __attribute__((ext_vector_type(4)));

#if __has_builtin(__builtin_amdgcn_exp2f)
#define EXP2F(x) __builtin_amdgcn_exp2f(x)
#else
#define EXP2F(x) exp2f(x)
#endif
#if __has_builtin(__builtin_amdgcn_rcpf)
#define RCPF(x) __builtin_amdgcn_rcpf(x)
#else
#define RCPF(x) (1.0f / (x))
#endif

// Inputs pre-scaled: a' = 2*log2e*a, g' = log2e*g, r' = SCALEF*r.
__device__ __forceinline__ float gatecomb(float a, float g, float rp) {
  const float u = EXP2F(a);
  const float v = EXP2F(g);
  const float num = fmaf(u, v, -v);            // (u-1)*v
  const float den = (u + 1.0f) * (v + 1.0f);
  return fmaf(num * RCPF(den), SCALEF, rp);
}

// -------- prep kernels (R8-identical) --------

__global__ void k_cond(const float* __restrict__ mgc, const float* __restrict__ cond_w,
                       const float* __restrict__ cond_b, _Float16* __restrict__ cond_h) {
  int idx = blockIdx.x * 256 + threadIdx.x;   // < 102400
  int n = idx >> 6, c = idx & 63;
  if (c >= 60) { cond_h[idx] = (_Float16)0.0f; return; }
  int u = n % USZ, f = n / USZ;
  float a = cond_b[u * 60 + c];
  const float* wr = cond_w + (u * 60 + c) * 60;
  const float* mr = mgc + f * 60;
#pragma unroll 10
  for (int m = 0; m < 60; ++m) a = fmaf(mr[m], wr[m], a);
  float e = EXP2F(a * L2E2);
  cond_h[idx] = (_Float16)((e - 1.0f) * RCPF(e + 1.0f));
}

__global__ void k_packB(const float* __restrict__ ccw, _Float16* __restrict__ wfrag2) {
  int idx = blockIdx.x * 256 + threadIdx.x;   // < 327680
  int j    = idx & 7;
  int lane = (idx >> 3) & 63;
  int ks   = (idx >> 9) & 1;
  int nt   = (idx >> 10) & 7;
  int sl   = idx >> 13;                       // < 40
  int jo = nt * 16 + (lane & 15);
  int c  = ks * 32 + (lane >> 4) * 8 + j;
  float v = 0.0f;
  if (c < 60) v = ccw[((sl * 2 + (jo >> 6)) * 64 + (jo & 63)) * 60 + c];
  wfrag2[idx] = (_Float16)v;
}

__global__ void k_icgc_mfma(const _Float16* __restrict__ cond_h, const _Float16* __restrict__ wfrag2,
                            const float* __restrict__ ccb, const float* __restrict__ conv_b,
                            float* __restrict__ icgc) {
  const int n0 = blockIdx.x * 32;
  const int sl = blockIdx.y;
  const int tid = threadIdx.x;
  const int wave = tid >> 6, lane = tid & 63;
  const int m16 = lane & 15, q = lane >> 4;
  for (int t = wave; t < 16; t += 4) {
    const int mt = t >> 3, nt = t & 7;
    const int jo = nt * 16 + m16;
    const float b = ccb[(sl * 2 + (jo >> 6)) * 64 + (jo & 63)]
                  + conv_b[(sl * 3 + (jo >> 6)) * 64 + (jo & 63)];
    f32x4 acc = {b, b, b, b};
    const int arow = (n0 + mt * 16 + m16) * 64 + q * 8;
    const f16x8 a0 = *(const f16x8*)(cond_h + arow);
    const f16x8 a1 = *(const f16x8*)(cond_h + arow + 32);
    const f16x8* wb = (const f16x8*)wfrag2;
    const f16x8 b0 = wb[(((sl * 8 + nt) * 2 + 0) << 6) + lane];
    const f16x8 b1 = wb[(((sl * 8 + nt) * 2 + 1) << 6) + lane];
    acc = __builtin_amdgcn_mfma_f32_16x16x32_f16(a0, b0, acc, 0, 0, 0);
    acc = __builtin_amdgcn_mfma_f32_16x16x32_f16(a1, b1, acc, 0, 0, 0);
    const float gs = (jo >= 64) ? L2E : L2E2;   // gate pre-scale
#pragma unroll
    for (int r = 0; r < 4; ++r) {
      const int n = n0 + mt * 16 + q * 4 + r;
      icgc[((size_t)sl * 1600 + n) * 128 + jo] = acc[r] * gs;
    }
  }
}

__global__ void k_wcvt(const float* __restrict__ convs_w, _Float16* __restrict__ wfrag) {
  int idx = blockIdx.x * 256 + threadIdx.x;   // < 884736
  int j    = idx & 7;
  int lane = (idx >> 3) & 63;
  int ks   = (idx >> 9) & 3;
  int ch16 = (idx >> 11) & 3;
  int t    = idx >> 13;                       // sl*3 + gate
  int gate = t % 3, sl = t / 3;               // sl = s*9 + (l-1)
  int o  = ch16 * 16 + (lane & 15);
  int kk = ks * 32 + (lane >> 4) * 8 + j;
  int s2 = kk >> 6, c = kk & 63;
  const float gs = (gate == 0) ? L2E2 : ((gate == 1) ? L2E : SCALEF);
  wfrag[idx] = (_Float16)(convs_w[(((sl * 3 + gate) * 64 + o) * 64 + c) * 2 + s2] * gs);
}

__global__ void k_pwt(const float* __restrict__ pre_w, float* __restrict__ pwT) {
  int idx = blockIdx.x * 256 + threadIdx.x;   // < 65536
  int k = idx & 255, o = (idx >> 8) & 63, s = idx >> 14;
  pwT[idx] = pre_w[(s * 256 + k) * 64 + o];
}

__global__ void k_prefix(const float* __restrict__ noise, float* __restrict__ pxA,
                         float* __restrict__ pxB) {
  int i = blockIdx.x * 256 + threadIdx.x;     // < 1024
  float v = noise[i];
  pxA[i] = v; pxB[i] = v;
}

// -------- main per-window kernel (TPB=512, streamed LDS, 3 blocks/CU target) --------
// LDS layout (bytes):
//  X    @      0  (36864)  f16 [256 rows][CSTR]
//  Y    @  36864  ( 9216)  f16 [ 64 rows][CSTR]
//  scratch aliased into X rows 64.. (dead after l4; written only at l9/head):
//  x64f @   9216  (  256)
//  pre  @   9472  ( 1024)
//  red  @  10496  (   64)
#define SMEM_BYTES 46080

// One layer-visit over `nt` 16-row tiles. B-fragments loaded inside (visit scope).
__device__ __forceinline__ void tiles(
    const _Float16* __restrict__ inb, int in_row0,
    _Float16* __restrict__ outb, int out_row0, float* __restrict__ x64f,
    const _Float16* __restrict__ wfl,
    const float* __restrict__ icgc, const float* __restrict__ conv_b,
    int sl, int n, int nt, int Lout, bool last,
    int mstart, int q, int m16, int och, int lane, int ch16)
{
  if (mstart >= nt) return;
  const int base = (sl * 1600 + n) * 128;
  const float bi = icgc[base + och];
  const float bg = icgc[base + 64 + och];
  const float br = conv_b[(sl * 3 + 2) * 64 + och] * SCALEF;
  f16x8 bfr[3][4];
  const f16x8* wb = (const f16x8*)wfl;
#pragma unroll
  for (int g = 0; g < 3; ++g)
#pragma unroll
    for (int ks = 0; ks < 4; ++ks)
      bfr[g][ks] = wb[(((g * 4 + ch16) * 4 + ks) << 6) + lane];

#pragma unroll 1
  for (int mt = mstart; mt < nt; mt += 2) {
    f32x4 ai = {bi, bi, bi, bi};
    f32x4 ag = {bg, bg, bg, bg};
    f32x4 ar = {br, br, br, br};
#pragma unroll
    for (int ks = 0; ks < 4; ++ks) {
      const int row = in_row0 + 2 * (mt * 16 + m16) + (ks >> 1);
      const f16x8 af = *(const f16x8*)(inb + row * CSTR + (ks & 1) * 32 + q * 8);
      ai = __builtin_amdgcn_mfma_f32_16x16x32_f16(af, bfr[0][ks], ai, 0, 0, 0);
      ag = __builtin_amdgcn_mfma_f32_16x16x32_f16(af, bfr[1][ks], ag, 0, 0, 0);
      ar = __builtin_amdgcn_mfma_f32_16x16x32_f16(af, bfr[2][ks], ar, 0, 0, 0);
    }
#pragma unroll 2
    for (int r = 0; r < 4; ++r) {
      const int p = mt * 16 + q * 4 + r;
      const float val = gatecomb(ai[r], ag[r], ar[r]);
      if (last) { if (p == 0) x64f[och] = val; }
      else if (p < Lout) outb[(out_row0 + p) * CSTR + och] = (_Float16)val;
    }
  }
}

__launch_bounds__(TPB, 6)
__global__ void k_window(int s, const float* __restrict__ px, float* __restrict__ ptail,
                         float* __restrict__ out,
                         const float* __restrict__ icgc, const float* __restrict__ conv_b,
                         const float* __restrict__ conv0_w, const _Float16* __restrict__ wfrag,
                         const float* __restrict__ pwT, const float* __restrict__ pre_b,
                         const float* __restrict__ mean_w, const float* __restrict__ mean_b,
                         const float* __restrict__ std_w, const float* __restrict__ std_b) {
  extern __shared__ char smem[];
  _Float16* X    = (_Float16*)smem;
  _Float16* Y    = (_Float16*)(smem + 36864);
  float*    x64f = (float*)(smem + 9216);
  float*    pre  = (float*)(smem + 9472);
  float*    red  = (float*)(smem + 10496);

  const int n = blockIdx.x;
  const int tid = threadIdx.x;
  const int wave = tid >> 6, lane = tid & 63;
  const int q = lane >> 4, m16 = lane & 15;
  const int ch16 = wave & 3, mstart = wave >> 2;   // 8 waves: 4 ch16 x 2 mstart
  const int och = ch16 * 16 + m16;
  const int s10 = s * 10;
  const _Float16* wf1 = wfrag + (size_t)(s * 9) * 24576;

  // ---- phase A: layer 0 (8 chunks of 64 rows via Y) + layer 1 (into X) ----
#pragma unroll 1
  for (int c = 0; c < 8; ++c) {
    {
      // layer-0 constants, reloaded per chunk (limits register liveness)
      const int b0 = (s10 * 1600 + n) * 128;
      const float l0bi = icgc[b0 + lane];
      const float l0bg = icgc[b0 + 64 + lane];
      const float l0br = conv_b[(s10 * 3 + 2) * 64 + lane] * SCALEF;
      const float wi0 = conv0_w[((s * 3 + 0) * 64 + lane) * 2 + 0] * L2E2;
      const float wi1 = conv0_w[((s * 3 + 0) * 64 + lane) * 2 + 1] * L2E2;
      const float wg0 = conv0_w[((s * 3 + 1) * 64 + lane) * 2 + 0] * L2E;
      const float wg1 = conv0_w[((s * 3 + 1) * 64 + lane) * 2 + 1] * L2E;
      const float wr0 = conv0_w[((s * 3 + 2) * 64 + lane) * 2 + 0] * SCALEF;
      const float wr1 = conv0_w[((s * 3 + 2) * 64 + lane) * 2 + 1] * SCALEF;
#pragma unroll 1
      for (int r = wave; r < 64; r += 8) {
        const int pg = c * 64 + r;
        const float x0 = px[n + 2 * pg];
        const float x1 = px[n + 2 * pg + 1];
        const float vi = fmaf(x1, wi1, fmaf(x0, wi0, l0bi));
        const float vg = fmaf(x1, wg1, fmaf(x0, wg0, l0bg));
        const float vr = fmaf(x1, wr1, fmaf(x0, wr0, l0br));
        Y[r * CSTR + lane] = (_Float16)gatecomb(vi, vg, vr);
      }
    }
    __syncthreads();
    // layer 1 chunk: 2 tiles -> X rows [32c, 32c+32)
    tiles(Y, 0, X, 32 * c, x64f, wf1, icgc, conv_b, s10 + 1, n,
          2, 32, false, mstart, q, m16, och, lane, ch16);
    __syncthreads();
  }

  // ---- phase B: l2/l3 streamed in 2 chunks; l4..l9 ping-pong ----
#pragma unroll 1
  for (int c = 0; c < 2; ++c) {
    // l2 chunk: reads X[128c..128c+128), writes Y[0..63]
    tiles(X, 128 * c, Y, 0, x64f, wfrag + (size_t)(s * 9 + 1) * 24576, icgc, conv_b,
          s10 + 2, n, 4, 64, false, mstart, q, m16, och, lane, ch16);
    __syncthreads();
    // l3 chunk: reads Y[0..63], writes X[32c..32c+32)
    tiles(Y, 0, X, 32 * c, x64f, wfrag + (size_t)(s * 9 + 2) * 24576, icgc, conv_b,
          s10 + 3, n, 2, 32, false, mstart, q, m16, och, lane, ch16);
    __syncthreads();
  }
#pragma unroll 1
  for (int l = 4; l <= 9; ++l) {
    const int Lout = 512 >> l;
    const int nt = (Lout + 15) >> 4;          // 2,1,1,1,1,1
    const bool evenl = (l & 1) == 0;
    const _Float16* inb = evenl ? X : Y;      // l4: X->Y, l5: Y->X, ...
    _Float16* outb      = evenl ? Y : X;
    tiles(inb, 0, outb, 0, x64f, wfrag + (size_t)(s * 9 + (l - 1)) * 24576, icgc, conv_b,
          s10 + l, n, nt, Lout, l == 9, mstart, q, m16, och, lane, ch16);
    __syncthreads();
  }

  // ---- head ----
  if (tid < 256) {
    const int k = tid;
    float a = pre_b[s * 256 + k];
#pragma unroll 8
    for (int oo = 0; oo < 64; ++oo)
      a = fmaf(x64f[oo], pwT[(s * 64 + oo) * 256 + k], a);
    pre[k] = fmaxf(a, 0.0f);
  }
  __syncthreads();
  {
    float pm = 0.0f, pv = 0.0f;
    if (tid < 256) {
      float pk = pre[tid];
      pm = pk * mean_w[s * 256 + tid];
      pv = pk * std_w[s * 256 + tid];
    }
    for (int off = 32; off >= 1; off >>= 1) {
      pm += __shfl_down(pm, off, 64);
      pv += __shfl_down(pv, off, 64);
    }
    if (lane == 0) { red[wave] = pm; red[8 + wave] = pv; }
  }
  __syncthreads();
  if (tid == 0) {
    float m = mean_b[s], lv = std_b[s];
#pragma unroll
    for (int w2 = 0; w2 < 8; ++w2) { m += red[w2]; lv += red[8 + w2]; }
    float eps = px[n + RF];
    float nv = eps * __expf(0.5f * lv) + m;
    if (s == 3) { out[n] = nv; out[1600 + n] = m; out[3200 + n] = lv; }
    else ptail[n] = nv;
    if (n >= 576) out[4800 + s * 1024 + (n - 576)] = nv;   // tails: new[-1024:]
  }
}

extern "C" void kernel_launch(void* const* d_in, const int* in_sizes, int n_in,
                              void* d_out, int out_size, void* d_ws, size_t ws_size,
                              hipStream_t stream) {
  (void)in_sizes; (void)n_in; (void)out_size; (void)ws_size;
  const float* mgc     = (const float*)d_in[0];
  const float* noise   = (const float*)d_in[1];
  const float* cond_w  = (const float*)d_in[2];
  const float* cond_b  = (const float*)d_in[3];
  const float* conv0_w = (const float*)d_in[4];
  const float* convs_w = (const float*)d_in[5];
  const float* conv_b  = (const float*)d_in[6];
  const float* ccw     = (const float*)d_in[7];
  const float* ccb     = (const float*)d_in[8];
  const float* pre_w   = (const float*)d_in[9];
  const float* pre_b   = (const float*)d_in[10];
  const float* mean_w  = (const float*)d_in[11];
  const float* mean_b  = (const float*)d_in[12];
  const float* std_w   = (const float*)d_in[13];
  const float* std_b   = (const float*)d_in[14];
  float* out = (float*)d_out;

  char* ws = (char*)d_ws;
  float*    icgc   = (float*)ws;                         // 8,192,000 f = 32,768,000 B
  float*    pxA    = (float*)(ws + 32768000);            // 2624 f
  float*    pxB    = (float*)(ws + 32778496);            // 2624 f
  float*    pwT    = (float*)(ws + 32788992);            // 65536 f
  _Float16* wfrag  = (_Float16*)(ws + 33051136);         // 884736 h
  _Float16* wfrag2 = (_Float16*)(ws + 34820608);         // 327680 h
  _Float16* cond_h = (_Float16*)(ws + 35475968);         // 102400 h -> ends 35680768

  k_cond<<<400, 256, 0, stream>>>(mgc, cond_w, cond_b, cond_h);
  k_packB<<<1280, 256, 0, stream>>>(ccw, wfrag2);
  k_icgc_mfma<<<dim3(50, 40), 256, 0, stream>>>(cond_h, wfrag2, ccb, conv_b, icgc);
  k_wcvt<<<3456, 256, 0, stream>>>(convs_w, wfrag);
  k_pwt<<<256, 256, 0, stream>>>(pre_w, pwT);
  k_prefix<<<4, 256, 0, stream>>>(noise, pxA, pxB);

  (void)hipFuncSetAttribute((const void*)k_window,
                            hipFuncAttributeMaxDynamicSharedMemorySize, SMEM_BYTES);

  for (int s = 0; s < 4; ++s) {
    const float* pin = (s == 0) ? noise : (s == 1 ? pxA : (s == 2 ? pxB : pxA));
    float* pt = (s == 0) ? (pxA + 1024) : (s == 1 ? (pxB + 1024) : (s == 2 ? (pxA + 1024) : nullptr));
    k_window<<<NWIN, TPB, SMEM_BYTES, stream>>>(s, pin, pt, out, icgc, conv_b, conv0_w,
                                                wfrag, pwT, pre_b, mean_w, mean_b, std_w, std_b);
  }
}

// Round 10
// 762.627 us; speedup vs baseline: 1.5883x; 1.5883x over previous
//
#include <hip/hip_runtime.h>
#include <hip/hip_fp16.h>

// Problem constants
#define RF    1024
#define USZ   200
#define NWIN  1600          // N = 8 * 200
#define SCALEF 0.70710678118f
#define L2E2  2.885390082f  // 2*log2(e)
#define L2E   1.442695041f  // log2(e)
#define TPB   512
#define CSTR  72            // act channel stride in halfs (144 B rows, conflict-free)

typedef _Float16 f16x8 __attribute__((ext_vector_type(8)));
typedef float    f32x4 __attribute__((ext_vector_type(4)));

#if __has_builtin(__builtin_amdgcn_exp2f)
#define EXP2F(x) __builtin_amdgcn_exp2f(x)
#else
#define EXP2F(x) exp2f(x)
#endif
#if __has_builtin(__builtin_amdgcn_rcpf)
#define RCPF(x) __builtin_amdgcn_rcpf(x)
#else
#define RCPF(x) (1.0f / (x))
#endif

#define MFMA16(a, b, c) __builtin_amdgcn_mfma_f32_16x16x32_f16((a), (b), (c), 0, 0, 0)

// Inputs pre-scaled: a' = 2*log2e*a, g' = log2e*g, r' = SCALEF*r.
__device__ __forceinline__ float gatecomb(float a, float g, float rp) {
  const float u = EXP2F(a);
  const float v = EXP2F(g);
  const float num = fmaf(u, v, -v);            // (u-1)*v
  const float den = (u + 1.0f) * (v + 1.0f);
  return fmaf(num * RCPF(den), SCALEF, rp);
}

// -------- prep kernels (R8-identical) --------

__global__ void k_cond(const float* __restrict__ mgc, const float* __restrict__ cond_w,
                       const float* __restrict__ cond_b, _Float16* __restrict__ cond_h) {
  int idx = blockIdx.x * 256 + threadIdx.x;   // < 102400
  int n = idx >> 6, c = idx & 63;
  if (c >= 60) { cond_h[idx] = (_Float16)0.0f; return; }
  int u = n % USZ, f = n / USZ;
  float a = cond_b[u * 60 + c];
  const float* wr = cond_w + (u * 60 + c) * 60;
  const float* mr = mgc + f * 60;
#pragma unroll 10
  for (int m = 0; m < 60; ++m) a = fmaf(mr[m], wr[m], a);
  float e = EXP2F(a * L2E2);
  cond_h[idx] = (_Float16)((e - 1.0f) * RCPF(e + 1.0f));
}

__global__ void k_packB(const float* __restrict__ ccw, _Float16* __restrict__ wfrag2) {
  int idx = blockIdx.x * 256 + threadIdx.x;   // < 327680
  int j    = idx & 7;
  int lane = (idx >> 3) & 63;
  int ks   = (idx >> 9) & 1;
  int nt   = (idx >> 10) & 7;
  int sl   = idx >> 13;                       // < 40
  int jo = nt * 16 + (lane & 15);
  int c  = ks * 32 + (lane >> 4) * 8 + j;
  float v = 0.0f;
  if (c < 60) v = ccw[((sl * 2 + (jo >> 6)) * 64 + (jo & 63)) * 60 + c];
  wfrag2[idx] = (_Float16)v;
}

__global__ void k_icgc_mfma(const _Float16* __restrict__ cond_h, const _Float16* __restrict__ wfrag2,
                            const float* __restrict__ ccb, const float* __restrict__ conv_b,
                            float* __restrict__ icgc) {
  const int n0 = blockIdx.x * 32;
  const int sl = blockIdx.y;
  const int tid = threadIdx.x;
  const int wave = tid >> 6, lane = tid & 63;
  const int m16 = lane & 15, q = lane >> 4;
  for (int t = wave; t < 16; t += 4) {
    const int mt = t >> 3, nt = t & 7;
    const int jo = nt * 16 + m16;
    const float b = ccb[(sl * 2 + (jo >> 6)) * 64 + (jo & 63)]
                  + conv_b[(sl * 3 + (jo >> 6)) * 64 + (jo & 63)];
    f32x4 acc = {b, b, b, b};
    const int arow = (n0 + mt * 16 + m16) * 64 + q * 8;
    const f16x8 a0 = *(const f16x8*)(cond_h + arow);
    const f16x8 a1 = *(const f16x8*)(cond_h + arow + 32);
    const f16x8* wb = (const f16x8*)wfrag2;
    const f16x8 b0 = wb[(((sl * 8 + nt) * 2 + 0) << 6) + lane];
    const f16x8 b1 = wb[(((sl * 8 + nt) * 2 + 1) << 6) + lane];
    acc = MFMA16(a0, b0, acc);
    acc = MFMA16(a1, b1, acc);
    const float gs = (jo >= 64) ? L2E : L2E2;   // gate pre-scale
#pragma unroll
    for (int r = 0; r < 4; ++r) {
      const int n = n0 + mt * 16 + q * 4 + r;
      icgc[((size_t)sl * 1600 + n) * 128 + jo] = acc[r] * gs;
    }
  }
}

__global__ void k_wcvt(const float* __restrict__ convs_w, _Float16* __restrict__ wfrag) {
  int idx = blockIdx.x * 256 + threadIdx.x;   // < 884736
  int j    = idx & 7;
  int lane = (idx >> 3) & 63;
  int ks   = (idx >> 9) & 3;
  int ch16 = (idx >> 11) & 3;
  int t    = idx >> 13;                       // sl*3 + gate
  int gate = t % 3, sl = t / 3;               // sl = s*9 + (l-1)
  int o  = ch16 * 16 + (lane & 15);
  int kk = ks * 32 + (lane >> 4) * 8 + j;
  int s2 = kk >> 6, c = kk & 63;
  const float gs = (gate == 0) ? L2E2 : ((gate == 1) ? L2E : SCALEF);
  wfrag[idx] = (_Float16)(convs_w[(((sl * 3 + gate) * 64 + o) * 64 + c) * 2 + s2] * gs);
}

__global__ void k_pwt(const float* __restrict__ pre_w, float* __restrict__ pwT) {
  int idx = blockIdx.x * 256 + threadIdx.x;   // < 65536
  int k = idx & 255, o = (idx >> 8) & 63, s = idx >> 14;
  pwT[idx] = pre_w[(s * 256 + k) * 64 + o];
}

__global__ void k_prefix(const float* __restrict__ noise, float* __restrict__ pxA,
                         float* __restrict__ pxB) {
  int i = blockIdx.x * 256 + threadIdx.x;     // < 1024
  float v = noise[i];
  pxA[i] = v; pxB[i] = v;
}

// -------- main per-window kernel (TPB=512, streamed LDS, ks-outer K-loop) --------
// LDS layout (bytes):
//  X    @      0  (36864)  f16 [256 rows][CSTR]
//  Y    @  36864  ( 9216)  f16 [ 64 rows][CSTR]
//  scratch aliased into X rows 64.. (dead after l3; written only at l9/head):
//  x64f @   9216  (  256)
//  pre  @   9472  ( 1024)
//  red  @  10496  (   64)
#define SMEM_BYTES 46080

__device__ __forceinline__ void epilogue16(
    f32x4 ai, f32x4 ag, f32x4 ar, int mt, int Lout, bool last,
    _Float16* __restrict__ outb, int out_row0, float* __restrict__ x64f,
    int q, int och)
{
#pragma unroll 2
  for (int r = 0; r < 4; ++r) {
    const int p = mt * 16 + q * 4 + r;
    const float val = gatecomb(ai[r], ag[r], ar[r]);
    if (last) { if (p == 0) x64f[och] = val; }
    else if (p < Lout) outb[(out_row0 + p) * CSTR + och] = (_Float16)val;
  }
}

// One layer-visit over `nt` 16-row tiles, ks-outer to keep <=12 B-frag regs live.
__device__ __forceinline__ void tiles(
    const _Float16* __restrict__ inb, int in_row0,
    _Float16* __restrict__ outb, int out_row0, float* __restrict__ x64f,
    const _Float16* __restrict__ wfl,
    const float* __restrict__ icgc, const float* __restrict__ conv_b,
    int sl, int n, int nt, int Lout, bool last,
    int mstart, int q, int m16, int och, int lane, int ch16)
{
  if (mstart >= nt) return;
  const int base = (sl * 1600 + n) * 128;
  const float bi = icgc[base + och];
  const float bg = icgc[base + 64 + och];
  const float br = conv_b[(sl * 3 + 2) * 64 + och] * SCALEF;

  const int mt0 = mstart;
  const int mt1 = mstart + 2;
  const bool two = (mt1 < nt);

  f32x4 ai0 = {bi, bi, bi, bi}, ag0 = {bg, bg, bg, bg}, ar0 = {br, br, br, br};
  f32x4 ai1 = ai0, ag1 = ag0, ar1 = ar0;

  const f16x8* wb = (const f16x8*)wfl;
#pragma unroll 1
  for (int ks = 0; ks < 4; ++ks) {
    // 3 B-fragments for this ks only (12 VGPRs live)
    const f16x8 b0 = wb[(((0 * 4 + ch16) * 4 + ks) << 6) + lane];
    const f16x8 b1 = wb[(((1 * 4 + ch16) * 4 + ks) << 6) + lane];
    const f16x8 b2 = wb[(((2 * 4 + ch16) * 4 + ks) << 6) + lane];
    {
      const int row = in_row0 + 2 * (mt0 * 16 + m16) + (ks >> 1);
      const f16x8 af = *(const f16x8*)(inb + row * CSTR + (ks & 1) * 32 + q * 8);
      ai0 = MFMA16(af, b0, ai0);
      ag0 = MFMA16(af, b1, ag0);
      ar0 = MFMA16(af, b2, ar0);
    }
    if (two) {
      const int row = in_row0 + 2 * (mt1 * 16 + m16) + (ks >> 1);
      const f16x8 af = *(const f16x8*)(inb + row * CSTR + (ks & 1) * 32 + q * 8);
      ai1 = MFMA16(af, b0, ai1);
      ag1 = MFMA16(af, b1, ag1);
      ar1 = MFMA16(af, b2, ar1);
    }
  }
  epilogue16(ai0, ag0, ar0, mt0, Lout, last, outb, out_row0, x64f, q, och);
  if (two) epilogue16(ai1, ag1, ar1, mt1, Lout, last, outb, out_row0, x64f, q, och);
}

__launch_bounds__(TPB, 6)
__global__ void k_window(int s, const float* __restrict__ px, float* __restrict__ ptail,
                         float* __restrict__ out,
                         const float* __restrict__ icgc, const float* __restrict__ conv_b,
                         const float* __restrict__ conv0_w, const _Float16* __restrict__ wfrag,
                         const float* __restrict__ pwT, const float* __restrict__ pre_b,
                         const float* __restrict__ mean_w, const float* __restrict__ mean_b,
                         const float* __restrict__ std_w, const float* __restrict__ std_b) {
  extern __shared__ char smem[];
  _Float16* X    = (_Float16*)smem;
  _Float16* Y    = (_Float16*)(smem + 36864);
  float*    x64f = (float*)(smem + 9216);
  float*    pre  = (float*)(smem + 9472);
  float*    red  = (float*)(smem + 10496);

  const int n = blockIdx.x;
  const int tid = threadIdx.x;
  const int wave = tid >> 6, lane = tid & 63;
  const int q = lane >> 4, m16 = lane & 15;
  const int ch16 = wave & 3, mstart = wave >> 2;   // 8 waves: 4 ch16 x 2 mstart
  const int och = ch16 * 16 + m16;
  const int s10 = s * 10;
  const _Float16* wf1 = wfrag + (size_t)(s * 9) * 24576;

  // ---- phase A: layer 0 (8 chunks of 64 rows via Y) + layer 1 (into X) ----
#pragma unroll 1
  for (int c = 0; c < 8; ++c) {
    {
      // layer-0 constants, reloaded per chunk (limits register liveness)
      const int b0 = (s10 * 1600 + n) * 128;
      const float l0bi = icgc[b0 + lane];
      const float l0bg = icgc[b0 + 64 + lane];
      const float l0br = conv_b[(s10 * 3 + 2) * 64 + lane] * SCALEF;
      const float wi0 = conv0_w[((s * 3 + 0) * 64 + lane) * 2 + 0] * L2E2;
      const float wi1 = conv0_w[((s * 3 + 0) * 64 + lane) * 2 + 1] * L2E2;
      const float wg0 = conv0_w[((s * 3 + 1) * 64 + lane) * 2 + 0] * L2E;
      const float wg1 = conv0_w[((s * 3 + 1) * 64 + lane) * 2 + 1] * L2E;
      const float wr0 = conv0_w[((s * 3 + 2) * 64 + lane) * 2 + 0] * SCALEF;
      const float wr1 = conv0_w[((s * 3 + 2) * 64 + lane) * 2 + 1] * SCALEF;
#pragma unroll 1
      for (int r = wave; r < 64; r += 8) {
        const int pg = c * 64 + r;
        const float x0 = px[n + 2 * pg];
        const float x1 = px[n + 2 * pg + 1];
        const float vi = fmaf(x1, wi1, fmaf(x0, wi0, l0bi));
        const float vg = fmaf(x1, wg1, fmaf(x0, wg0, l0bg));
        const float vr = fmaf(x1, wr1, fmaf(x0, wr0, l0br));
        Y[r * CSTR + lane] = (_Float16)gatecomb(vi, vg, vr);
      }
    }
    __syncthreads();
    // layer 1 chunk: 2 tiles -> X rows [32c, 32c+32)
    tiles(Y, 0, X, 32 * c, x64f, wf1, icgc, conv_b, s10 + 1, n,
          2, 32, false, mstart, q, m16, och, lane, ch16);
    __syncthreads();
  }

  // ---- phase B: l2/l3 streamed in 2 chunks; l4..l9 ping-pong ----
#pragma unroll 1
  for (int c = 0; c < 2; ++c) {
    // l2 chunk: reads X[128c..128c+128), writes Y[0..63]
    tiles(X, 128 * c, Y, 0, x64f, wfrag + (size_t)(s * 9 + 1) * 24576, icgc, conv_b,
          s10 + 2, n, 4, 64, false, mstart, q, m16, och, lane, ch16);
    __syncthreads();
    // l3 chunk: reads Y[0..63], writes X[32c..32c+32)
    tiles(Y, 0, X, 32 * c, x64f, wfrag + (size_t)(s * 9 + 2) * 24576, icgc, conv_b,
          s10 + 3, n, 2, 32, false, mstart, q, m16, och, lane, ch16);
    __syncthreads();
  }
#pragma unroll 1
  for (int l = 4; l <= 9; ++l) {
    const int Lout = 512 >> l;
    const int nt = (Lout + 15) >> 4;          // 2,1,1,1,1,1
    const bool evenl = (l & 1) == 0;
    const _Float16* inb = evenl ? X : Y;
    _Float16* outb      = evenl ? Y : X;
    tiles(inb, 0, outb, 0, x64f, wfrag + (size_t)(s * 9 + (l - 1)) * 24576, icgc, conv_b,
          s10 + l, n, nt, Lout, l == 9, mstart, q, m16, och, lane, ch16);
    __syncthreads();
  }

  // ---- head ----
  if (tid < 256) {
    const int k = tid;
    float a = pre_b[s * 256 + k];
#pragma unroll 8
    for (int oo = 0; oo < 64; ++oo)
      a = fmaf(x64f[oo], pwT[(s * 64 + oo) * 256 + k], a);
    pre[k] = fmaxf(a, 0.0f);
  }
  __syncthreads();
  {
    float pm = 0.0f, pv = 0.0f;
    if (tid < 256) {
      float pk = pre[tid];
      pm = pk * mean_w[s * 256 + tid];
      pv = pk * std_w[s * 256 + tid];
    }
    for (int off = 32; off >= 1; off >>= 1) {
      pm += __shfl_down(pm, off, 64);
      pv += __shfl_down(pv, off, 64);
    }
    if (lane == 0) { red[wave] = pm; red[8 + wave] = pv; }
  }
  __syncthreads();
  if (tid == 0) {
    float m = mean_b[s], lv = std_b[s];
#pragma unroll
    for (int w2 = 0; w2 < 8; ++w2) { m += red[w2]; lv += red[8 + w2]; }
    float eps = px[n + RF];
    float nv = eps * __expf(0.5f * lv) + m;
    if (s == 3) { out[n] = nv; out[1600 + n] = m; out[3200 + n] = lv; }
    else ptail[n] = nv;
    if (n >= 576) out[4800 + s * 1024 + (n - 576)] = nv;   // tails: new[-1024:]
  }
}

extern "C" void kernel_launch(void* const* d_in, const int* in_sizes, int n_in,
                              void* d_out, int out_size, void* d_ws, size_t ws_size,
                              hipStream_t stream) {
  (void)in_sizes; (void)n_in; (void)out_size; (void)ws_size;
  const float* mgc     = (const float*)d_in[0];
  const float* noise   = (const float*)d_in[1];
  const float* cond_w  = (const float*)d_in[2];
  const float* cond_b  = (const float*)d_in[3];
  const float* conv0_w = (const float*)d_in[4];
  const float* convs_w = (const float*)d_in[5];
  const float* conv_b  = (const float*)d_in[6];
  const float* ccw     = (const float*)d_in[7];
  const float* ccb     = (const float*)d_in[8];
  const float* pre_w   = (const float*)d_in[9];
  const float* pre_b   = (const float*)d_in[10];
  const float* mean_w  = (const float*)d_in[11];
  const float* mean_b  = (const float*)d_in[12];
  const float* std_w   = (const float*)d_in[13];
  const float* std_b   = (const float*)d_in[14];
  float* out = (float*)d_out;

  char* ws = (char*)d_ws;
  float*    icgc   = (float*)ws;                         // 8,192,000 f = 32,768,000 B
  float*    pxA    = (float*)(ws + 32768000);            // 2624 f
  float*    pxB    = (float*)(ws + 32778496);            // 2624 f
  float*    pwT    = (float*)(ws + 32788992);            // 65536 f
  _Float16* wfrag  = (_Float16*)(ws + 33051136);         // 884736 h
  _Float16* wfrag2 = (_Float16*)(ws + 34820608);         // 327680 h
  _Float16* cond_h = (_Float16*)(ws + 35475968);         // 102400 h -> ends 35680768

  k_cond<<<400, 256, 0, stream>>>(mgc, cond_w, cond_b, cond_h);
  k_packB<<<1280, 256, 0, stream>>>(ccw, wfrag2);
  k_icgc_mfma<<<dim3(50, 40), 256, 0, stream>>>(cond_h, wfrag2, ccb, conv_b, icgc);
  k_wcvt<<<3456, 256, 0, stream>>>(convs_w, wfrag);
  k_pwt<<<256, 256, 0, stream>>>(pre_w, pwT);
  k_prefix<<<4, 256, 0, stream>>>(noise, pxA, pxB);

  (void)hipFuncSetAttribute((const void*)k_window,
                            hipFuncAttributeMaxDynamicSharedMemorySize, SMEM_BYTES);

  for (int s = 0; s < 4; ++s) {
    const float* pin = (s == 0) ? noise : (s == 1 ? pxA : (s == 2 ? pxB : pxA));
    float* pt = (s == 0) ? (pxA + 1024) : (s == 1 ? (pxB + 1024) : (s == 2 ? (pxA + 1024) : nullptr));
    k_window<<<NWIN, TPB, SMEM_BYTES, stream>>>(s, pin, pt, out, icgc, conv_b, conv0_w,
                                                wfrag, pwT, pre_b, mean_w, mean_b, std_w, std_b);
  }
}

// Round 11
// 698.758 us; speedup vs baseline: 1.7335x; 1.0914x over previous
//
#include <hip/hip_runtime.h>
#include <hip/hip_fp16.h>

// Problem constants
#define RF    1024
#define USZ   200
#define NWIN  1600          // N = 8 * 200
#define SCALEF 0.70710678118f
#define L2E2  2.885390082f  // 2*log2(e)
#define L2E   1.442695041f  // log2(e)
#define TPB   768           // 12 waves: 4 ch16 x 3 mstart
#define MSTEP 3
#define CSTR  72            // act channel stride in halfs (144 B rows, conflict-free)

typedef _Float16 f16x8 __attribute__((ext_vector_type(8)));
typedef float    f32x4 __attribute__((ext_vector_type(4)));

#if __has_builtin(__builtin_amdgcn_exp2f)
#define EXP2F(x) __builtin_amdgcn_exp2f(x)
#else
#define EXP2F(x) exp2f(x)
#endif
#if __has_builtin(__builtin_amdgcn_rcpf)
#define RCPF(x) __builtin_amdgcn_rcpf(x)
#else
#define RCPF(x) (1.0f / (x))
#endif

#define MFMA16(a, b, c) __builtin_amdgcn_mfma_f32_16x16x32_f16((a), (b), (c), 0, 0, 0)

// Inputs pre-scaled: a' = 2*log2e*a, g' = log2e*g, r' = SCALEF*r.
__device__ __forceinline__ float gatecomb(float a, float g, float rp) {
  const float u = EXP2F(a);
  const float v = EXP2F(g);
  const float num = fmaf(u, v, -v);            // (u-1)*v
  const float den = (u + 1.0f) * (v + 1.0f);
  return fmaf(num * RCPF(den), SCALEF, rp);
}

// -------- prep kernels (R8-identical) --------

__global__ void k_cond(const float* __restrict__ mgc, const float* __restrict__ cond_w,
                       const float* __restrict__ cond_b, _Float16* __restrict__ cond_h) {
  int idx = blockIdx.x * 256 + threadIdx.x;   // < 102400
  int n = idx >> 6, c = idx & 63;
  if (c >= 60) { cond_h[idx] = (_Float16)0.0f; return; }
  int u = n % USZ, f = n / USZ;
  float a = cond_b[u * 60 + c];
  const float* wr = cond_w + (u * 60 + c) * 60;
  const float* mr = mgc + f * 60;
#pragma unroll 10
  for (int m = 0; m < 60; ++m) a = fmaf(mr[m], wr[m], a);
  float e = EXP2F(a * L2E2);
  cond_h[idx] = (_Float16)((e - 1.0f) * RCPF(e + 1.0f));
}

__global__ void k_packB(const float* __restrict__ ccw, _Float16* __restrict__ wfrag2) {
  int idx = blockIdx.x * 256 + threadIdx.x;   // < 327680
  int j    = idx & 7;
  int lane = (idx >> 3) & 63;
  int ks   = (idx >> 9) & 1;
  int nt   = (idx >> 10) & 7;
  int sl   = idx >> 13;                       // < 40
  int jo = nt * 16 + (lane & 15);
  int c  = ks * 32 + (lane >> 4) * 8 + j;
  float v = 0.0f;
  if (c < 60) v = ccw[((sl * 2 + (jo >> 6)) * 64 + (jo & 63)) * 60 + c];
  wfrag2[idx] = (_Float16)v;
}

__global__ void k_icgc_mfma(const _Float16* __restrict__ cond_h, const _Float16* __restrict__ wfrag2,
                            const float* __restrict__ ccb, const float* __restrict__ conv_b,
                            float* __restrict__ icgc) {
  const int n0 = blockIdx.x * 32;
  const int sl = blockIdx.y;
  const int tid = threadIdx.x;
  const int wave = tid >> 6, lane = tid & 63;
  const int m16 = lane & 15, q = lane >> 4;
  for (int t = wave; t < 16; t += 4) {
    const int mt = t >> 3, nt = t & 7;
    const int jo = nt * 16 + m16;
    const float b = ccb[(sl * 2 + (jo >> 6)) * 64 + (jo & 63)]
                  + conv_b[(sl * 3 + (jo >> 6)) * 64 + (jo & 63)];
    f32x4 acc = {b, b, b, b};
    const int arow = (n0 + mt * 16 + m16) * 64 + q * 8;
    const f16x8 a0 = *(const f16x8*)(cond_h + arow);
    const f16x8 a1 = *(const f16x8*)(cond_h + arow + 32);
    const f16x8* wb = (const f16x8*)wfrag2;
    const f16x8 b0 = wb[(((sl * 8 + nt) * 2 + 0) << 6) + lane];
    const f16x8 b1 = wb[(((sl * 8 + nt) * 2 + 1) << 6) + lane];
    acc = MFMA16(a0, b0, acc);
    acc = MFMA16(a1, b1, acc);
    const float gs = (jo >= 64) ? L2E : L2E2;   // gate pre-scale
#pragma unroll
    for (int r = 0; r < 4; ++r) {
      const int n = n0 + mt * 16 + q * 4 + r;
      icgc[((size_t)sl * 1600 + n) * 128 + jo] = acc[r] * gs;
    }
  }
}

__global__ void k_wcvt(const float* __restrict__ convs_w, _Float16* __restrict__ wfrag) {
  int idx = blockIdx.x * 256 + threadIdx.x;   // < 884736
  int j    = idx & 7;
  int lane = (idx >> 3) & 63;
  int ks   = (idx >> 9) & 3;
  int ch16 = (idx >> 11) & 3;
  int t    = idx >> 13;                       // sl*3 + gate
  int gate = t % 3, sl = t / 3;               // sl = s*9 + (l-1)
  int o  = ch16 * 16 + (lane & 15);
  int kk = ks * 32 + (lane >> 4) * 8 + j;
  int s2 = kk >> 6, c = kk & 63;
  const float gs = (gate == 0) ? L2E2 : ((gate == 1) ? L2E : SCALEF);
  wfrag[idx] = (_Float16)(convs_w[(((sl * 3 + gate) * 64 + o) * 64 + c) * 2 + s2] * gs);
}

__global__ void k_pwt(const float* __restrict__ pre_w, float* __restrict__ pwT) {
  int idx = blockIdx.x * 256 + threadIdx.x;   // < 65536
  int k = idx & 255, o = (idx >> 8) & 63, s = idx >> 14;
  pwT[idx] = pre_w[(s * 256 + k) * 64 + o];
}

__global__ void k_prefix(const float* __restrict__ noise, float* __restrict__ pxA,
                         float* __restrict__ pxB) {
  int i = blockIdx.x * 256 + threadIdx.x;     // < 1024
  float v = noise[i];
  pxA[i] = v; pxB[i] = v;
}

// -------- main per-window kernel (R8 structure + ks-outer regs + TPB=768) --------
// LDS layout (bytes):
//  bufA @      0  (36864)  f16 [256 rows][CSTR]
//  bufB @  36864  (36864)  f16 [256 rows][CSTR]
//  xw   @  73728  ( 4112)  fp32 window samples [1025]
//  x64f @  77840  (  256)
//  pre  @  78096  ( 1024)
//  red  @  79120  (  128)
#define SMEM_BYTES 79248

__device__ __forceinline__ void epilogue16(
    f32x4 ai, f32x4 ag, f32x4 ar, int mt, int Lout, bool last,
    _Float16* __restrict__ outb, float* __restrict__ x64f,
    int q, int och)
{
#pragma unroll 2
  for (int r = 0; r < 4; ++r) {
    const int p = mt * 16 + q * 4 + r;
    const float val = gatecomb(ai[r], ag[r], ar[r]);
    if (last) { if (p == 0) x64f[och] = val; }
    else if (p < Lout) outb[p * CSTR + och] = (_Float16)val;
  }
}

// Layer-visit over tiles mt_lo..mt_hi step MSTEP (pairs), ks-outer: <=12 B regs live.
__device__ __forceinline__ void tiles(
    const _Float16* __restrict__ ain, _Float16* __restrict__ aout, float* __restrict__ x64f,
    const _Float16* __restrict__ wfl,
    const float* __restrict__ icgc, const float* __restrict__ conv_b,
    int sl, int n, int mt_lo, int mt_hi, int row_sub, int Lout, bool last,
    int q, int m16, int och, int lane, int ch16)
{
  if (mt_lo >= mt_hi) return;
  const int base = (sl * 1600 + n) * 128;
  const float bi = icgc[base + och];
  const float bg = icgc[base + 64 + och];
  const float br = conv_b[(sl * 3 + 2) * 64 + och] * SCALEF;
  const f16x8* wb = (const f16x8*)wfl;

#pragma unroll 1
  for (int mt0 = mt_lo; mt0 < mt_hi; mt0 += 2 * MSTEP) {
    const int mt1 = mt0 + MSTEP;
    const bool two = (mt1 < mt_hi);
    f32x4 ai0 = {bi, bi, bi, bi}, ag0 = {bg, bg, bg, bg}, ar0 = {br, br, br, br};
    f32x4 ai1 = ai0, ag1 = ag0, ar1 = ar0;
#pragma unroll 1
    for (int ks = 0; ks < 4; ++ks) {
      const f16x8 b0 = wb[(((0 * 4 + ch16) * 4 + ks) << 6) + lane];
      const f16x8 b1 = wb[(((1 * 4 + ch16) * 4 + ks) << 6) + lane];
      const f16x8 b2 = wb[(((2 * 4 + ch16) * 4 + ks) << 6) + lane];
      {
        const int row = 2 * (mt0 * 16 + m16) + (ks >> 1) - row_sub;
        const f16x8 af = *(const f16x8*)(ain + row * CSTR + (ks & 1) * 32 + q * 8);
        ai0 = MFMA16(af, b0, ai0);
        ag0 = MFMA16(af, b1, ag0);
        ar0 = MFMA16(af, b2, ar0);
      }
      if (two) {
        const int row = 2 * (mt1 * 16 + m16) + (ks >> 1) - row_sub;
        const f16x8 af = *(const f16x8*)(ain + row * CSTR + (ks & 1) * 32 + q * 8);
        ai1 = MFMA16(af, b0, ai1);
        ag1 = MFMA16(af, b1, ag1);
        ar1 = MFMA16(af, b2, ar1);
      }
    }
    epilogue16(ai0, ag0, ar0, mt0, Lout, last, aout, x64f, q, och);
    if (two) epilogue16(ai1, ag1, ar1, mt1, Lout, last, aout, x64f, q, och);
  }
}

__launch_bounds__(TPB, 6)
__global__ void k_window(int s, const float* __restrict__ px, float* __restrict__ ptail,
                         float* __restrict__ out,
                         const float* __restrict__ icgc, const float* __restrict__ conv_b,
                         const float* __restrict__ conv0_w, const _Float16* __restrict__ wfrag,
                         const float* __restrict__ pwT, const float* __restrict__ pre_b,
                         const float* __restrict__ mean_w, const float* __restrict__ mean_b,
                         const float* __restrict__ std_w, const float* __restrict__ std_b) {
  extern __shared__ char smem[];
  _Float16* bufA = (_Float16*)smem;
  _Float16* bufB = (_Float16*)(smem + 36864);
  float*    xw   = (float*)(smem + 73728);
  float*    x64f = (float*)(smem + 77840);
  float*    pre  = (float*)(smem + 78096);
  float*    red  = (float*)(smem + 79120);

  const int n = blockIdx.x;
  const int tid = threadIdx.x;
  const int wave = tid >> 6, lane = tid & 63;
  const int q = lane >> 4, m16 = lane & 15;
  const int ch16 = wave & 3, mstart = wave >> 2;   // 12 waves: 4 ch16 x 3 mstart
  const int och = ch16 * 16 + m16;
  const int s10 = s * 10;

  // stage window samples
  for (int i = tid; i < 1025; i += TPB) xw[i] = px[n + i];

  // layer-0 per-lane constants (lane = channel), pre-scaled; held across phase A
  const int b0 = (s10 * 1600 + n) * 128;
  const float l0bi = icgc[b0 + lane];
  const float l0bg = icgc[b0 + 64 + lane];
  const float l0br = conv_b[(s10 * 3 + 2) * 64 + lane] * SCALEF;
  const float wi0 = conv0_w[((s * 3 + 0) * 64 + lane) * 2 + 0] * L2E2;
  const float wi1 = conv0_w[((s * 3 + 0) * 64 + lane) * 2 + 1] * L2E2;
  const float wg0 = conv0_w[((s * 3 + 1) * 64 + lane) * 2 + 0] * L2E;
  const float wg1 = conv0_w[((s * 3 + 1) * 64 + lane) * 2 + 1] * L2E;
  const float wr0 = conv0_w[((s * 3 + 2) * 64 + lane) * 2 + 0] * SCALEF;
  const float wr1 = conv0_w[((s * 3 + 2) * 64 + lane) * 2 + 1] * SCALEF;

  const _Float16* wf1 = wfrag + (size_t)(s * 9) * 24576;
  __syncthreads();

  // ---- layer 0 chunk 0: pos 0..255 -> bufA ----
#pragma unroll 1
  for (int p = wave; p < 256; p += 12) {
    const float x0 = xw[2 * p], x1 = xw[2 * p + 1];
    const float vi = fmaf(x1, wi1, fmaf(x0, wi0, l0bi));
    const float vg = fmaf(x1, wg1, fmaf(x0, wg0, l0bg));
    const float vr = fmaf(x1, wr1, fmaf(x0, wr0, l0br));
    bufA[p * CSTR + lane] = (_Float16)gatecomb(vi, vg, vr);
  }
  __syncthreads();

  // ---- layer 1 chunk A: tiles 0..7 <- bufA rows 0..255 ----
  tiles(bufA, bufB, x64f, wf1, icgc, conv_b, s10 + 1, n,
        mstart, 8, 0, 256, false, q, m16, och, lane, ch16);
  __syncthreads();

  // ---- layer 0 chunk 1: pos 256..511 -> bufA rows 0..255 ----
#pragma unroll 1
  for (int p = wave; p < 256; p += 12) {
    const int pg = 256 + p;
    const float x0 = xw[2 * pg], x1 = xw[2 * pg + 1];
    const float vi = fmaf(x1, wi1, fmaf(x0, wi0, l0bi));
    const float vg = fmaf(x1, wg1, fmaf(x0, wg0, l0bg));
    const float vr = fmaf(x1, wr1, fmaf(x0, wr0, l0br));
    bufA[p * CSTR + lane] = (_Float16)gatecomb(vi, vg, vr);
  }
  __syncthreads();

  // ---- layer 1 chunk B: tiles 8..15, rows offset by -256 ----
  tiles(bufA, bufB, x64f, wf1, icgc, conv_b, s10 + 1, n,
        8 + mstart, 16, 256, 256, false, q, m16, och, lane, ch16);
  __syncthreads();

  // ---- layers 2..9: ping-pong bufB/bufA ----
#pragma unroll 1
  for (int l = 2; l <= 9; ++l) {
    const int Lout = 512 >> l;
    const int nt = (Lout + 15) >> 4;
    const _Float16* ain = (l & 1) ? bufA : bufB;
    _Float16* aout      = (l & 1) ? bufB : bufA;
    tiles(ain, aout, x64f, wfrag + (size_t)(s * 9 + (l - 1)) * 24576, icgc, conv_b,
          s10 + l, n, mstart, nt, 0, Lout, l == 9, q, m16, och, lane, ch16);
    __syncthreads();
  }

  // ---- head ----
  if (tid < 256) {
    const int k = tid;
    float a = pre_b[s * 256 + k];
#pragma unroll 8
    for (int oo = 0; oo < 64; ++oo)
      a = fmaf(x64f[oo], pwT[(s * 64 + oo) * 256 + k], a);
    pre[k] = fmaxf(a, 0.0f);
  }
  __syncthreads();
  {
    float pm = 0.0f, pv = 0.0f;
    if (tid < 256) {
      float pk = pre[tid];
      pm = pk * mean_w[s * 256 + tid];
      pv = pk * std_w[s * 256 + tid];
    }
    for (int off = 32; off >= 1; off >>= 1) {
      pm += __shfl_down(pm, off, 64);
      pv += __shfl_down(pv, off, 64);
    }
    if (lane == 0) { red[wave] = pm; red[12 + wave] = pv; }
  }
  __syncthreads();
  if (tid == 0) {
    float m = mean_b[s], lv = std_b[s];
#pragma unroll
    for (int w2 = 0; w2 < 12; ++w2) { m += red[w2]; lv += red[12 + w2]; }
    float eps = xw[1024];                       // px[n + RF]
    float nv = eps * __expf(0.5f * lv) + m;
    if (s == 3) { out[n] = nv; out[1600 + n] = m; out[3200 + n] = lv; }
    else ptail[n] = nv;
    if (n >= 576) out[4800 + s * 1024 + (n - 576)] = nv;   // tails: new[-1024:]
  }
}

extern "C" void kernel_launch(void* const* d_in, const int* in_sizes, int n_in,
                              void* d_out, int out_size, void* d_ws, size_t ws_size,
                              hipStream_t stream) {
  (void)in_sizes; (void)n_in; (void)out_size; (void)ws_size;
  const float* mgc     = (const float*)d_in[0];
  const float* noise   = (const float*)d_in[1];
  const float* cond_w  = (const float*)d_in[2];
  const float* cond_b  = (const float*)d_in[3];
  const float* conv0_w = (const float*)d_in[4];
  const float* convs_w = (const float*)d_in[5];
  const float* conv_b  = (const float*)d_in[6];
  const float* ccw     = (const float*)d_in[7];
  const float* ccb     = (const float*)d_in[8];
  const float* pre_w   = (const float*)d_in[9];
  const float* pre_b   = (const float*)d_in[10];
  const float* mean_w  = (const float*)d_in[11];
  const float* mean_b  = (const float*)d_in[12];
  const float* std_w   = (const float*)d_in[13];
  const float* std_b   = (const float*)d_in[14];
  float* out = (float*)d_out;

  char* ws = (char*)d_ws;
  float*    icgc   = (float*)ws;                         // 8,192,000 f = 32,768,000 B
  float*    pxA    = (float*)(ws + 32768000);            // 2624 f
  float*    pxB    = (float*)(ws + 32778496);            // 2624 f
  float*    pwT    = (float*)(ws + 32788992);            // 65536 f
  _Float16* wfrag  = (_Float16*)(ws + 33051136);         // 884736 h
  _Float16* wfrag2 = (_Float16*)(ws + 34820608);         // 327680 h
  _Float16* cond_h = (_Float16*)(ws + 35475968);         // 102400 h -> ends 35680768

  k_cond<<<400, 256, 0, stream>>>(mgc, cond_w, cond_b, cond_h);
  k_packB<<<1280, 256, 0, stream>>>(ccw, wfrag2);
  k_icgc_mfma<<<dim3(50, 40), 256, 0, stream>>>(cond_h, wfrag2, ccb, conv_b, icgc);
  k_wcvt<<<3456, 256, 0, stream>>>(convs_w, wfrag);
  k_pwt<<<256, 256, 0, stream>>>(pre_w, pwT);
  k_prefix<<<4, 256, 0, stream>>>(noise, pxA, pxB);

  (void)hipFuncSetAttribute((const void*)k_window,
                            hipFuncAttributeMaxDynamicSharedMemorySize, SMEM_BYTES);

  for (int s = 0; s < 4; ++s) {
    const float* pin = (s == 0) ? noise : (s == 1 ? pxA : (s == 2 ? pxB : pxA));
    float* pt = (s == 0) ? (pxA + 1024) : (s == 1 ? (pxB + 1024) : (s == 2 ? (pxA + 1024) : nullptr));
    k_window<<<NWIN, TPB, SMEM_BYTES, stream>>>(s, pin, pt, out, icgc, conv_b, conv0_w,
                                                wfrag, pwT, pre_b, mean_w, mean_b, std_w, std_b);
  }
}